// Round 3
// baseline (645.602 us; speedup 1.0000x reference)
//
#include <hip/hip_runtime.h>

// GCN 2-layer collapsed (x is [N,1] => layer 1 is rank-1):
//   out[c] = dis[c]*(sum_{r->c} gp[r] + gp[c]) + b2,  gp[r] = (relu(W1*a[r]+b1)@W2)*dis[r]
//   a[r]   = dis[r]*(sum_{r'->r} p[r'] + p[r]),       p[r']=x[r']*dis[r'], dis=1/sqrt(deg+1)
//
// R1: global atomics = 20G/s fabric wall (3.1ms). R2: bucket sort + LDS atomics (478us),
// but partition's scattered 4B stores cost 390MB write-through for a 64MB array.
// R3: tile-local LDS counting sort in the partition -> coalesced run writes (~264B runs),
//     4096-node chunks (K=123) so aggregation uses 123 big blocks with 16-32KB LDS.

#define CSHIFT 12
#define CNODES 4096          // 1 << CSHIFT
#define CMAX   256           // max chunks supported (n <= 1M)

#define PTPB  512            // partition block
#define PU    16             // edges per thread
#define PTILE (PTPB * PU)    // 8192 edges per tile

#define ATPB  512            // aggregation block

// ---------- pass 0: zero chunk totals ----------
__global__ void k_zero(int* __restrict__ totals, int K) {
    int i = blockIdx.x * blockDim.x + threadIdx.x;
    if (i < K) totals[i] = 0;
}

// ---------- pass 1: chunk histogram ----------
__global__ void k_count(const int* __restrict__ col, int ne,
                        int* __restrict__ totals, int K) {
    __shared__ int cnt[CMAX];
    for (int i = threadIdx.x; i < K; i += blockDim.x) cnt[i] = 0;
    __syncthreads();
    int tid = blockIdx.x * blockDim.x + threadIdx.x;
    int stride = gridDim.x * blockDim.x;
    int ne4 = ne >> 2;
    const int4* col4 = (const int4*)col;
    for (int e = tid; e < ne4; e += stride) {
        int4 cc = col4[e];
        atomicAdd(&cnt[cc.x >> CSHIFT], 1);
        atomicAdd(&cnt[cc.y >> CSHIFT], 1);
        atomicAdd(&cnt[cc.z >> CSHIFT], 1);
        atomicAdd(&cnt[cc.w >> CSHIFT], 1);
    }
    for (int e = (ne4 << 2) + tid; e < ne; e += stride)
        atomicAdd(&cnt[col[e] >> CSHIFT], 1);
    __syncthreads();
    for (int i = threadIdx.x; i < K; i += blockDim.x)
        if (cnt[i]) atomicAdd(&totals[i], cnt[i]);
}

// ---------- pass 2: scan -> bbase, init cursors ----------
__global__ void k_scan(const int* __restrict__ totals, int* __restrict__ bbase,
                       int* __restrict__ cursor, int K) {
    if (threadIdx.x == 0 && blockIdx.x == 0) {
        int run = 0;
        for (int k = 0; k < K; ++k) {
            bbase[k] = run;
            cursor[k] = run;
            run += totals[k];
        }
        bbase[K] = run;
    }
}

// ---------- pass 3: partition with tile-local LDS counting sort ----------
__global__ __launch_bounds__(PTPB) void k_partition(
    const int* __restrict__ row, const int* __restrict__ col, int ne,
    int* __restrict__ cursor, int* __restrict__ packed, int K)
{
    __shared__ int s_cnt[CMAX];
    __shared__ int s_start[CMAX + 1];
    __shared__ int s_cur[CMAX];
    __shared__ int s_gbase[CMAX];
    __shared__ int s_sorted[PTILE];

    int tb = blockIdx.x * PTILE;
    int tilecount = ne - tb;
    if (tilecount > PTILE) tilecount = PTILE;

    for (int i = threadIdx.x; i < K; i += PTPB) s_cnt[i] = 0;
    __syncthreads();

    int r[PU], c[PU];
    const int4* row4 = (const int4*)row;
    const int4* col4 = (const int4*)col;
    int tb4 = tb >> 2;
#pragma unroll
    for (int j = 0; j < PU / 4; ++j) {
        int g4 = tb4 + j * PTPB + threadIdx.x;
        int e = g4 << 2;
        if (e + 3 < ne) {
            int4 rr = row4[g4];
            int4 cc = col4[g4];
            r[4 * j + 0] = rr.x; r[4 * j + 1] = rr.y; r[4 * j + 2] = rr.z; r[4 * j + 3] = rr.w;
            c[4 * j + 0] = cc.x; c[4 * j + 1] = cc.y; c[4 * j + 2] = cc.z; c[4 * j + 3] = cc.w;
        } else {
#pragma unroll
            for (int q = 0; q < 4; ++q) {
                int e2 = e + q;
                if (e2 < ne) { r[4 * j + q] = row[e2]; c[4 * j + q] = col[e2]; }
                else { r[4 * j + q] = 0; c[4 * j + q] = -1; }
            }
        }
    }
#pragma unroll
    for (int j = 0; j < PU; ++j)
        if (c[j] >= 0) atomicAdd(&s_cnt[c[j] >> CSHIFT], 1);
    __syncthreads();

    if (threadIdx.x == 0) {
        int run = 0;
        for (int k = 0; k < K; ++k) { s_start[k] = run; run += s_cnt[k]; }
        s_start[K] = run;  // == tilecount
    }
    __syncthreads();
    if ((int)threadIdx.x < K) {
        int n0 = s_cnt[threadIdx.x];
        s_gbase[threadIdx.x] = n0 ? atomicAdd(&cursor[threadIdx.x], n0) : 0;
        s_cur[threadIdx.x] = s_start[threadIdx.x];
    }
    __syncthreads();

#pragma unroll
    for (int j = 0; j < PU; ++j) {
        if (c[j] >= 0) {
            int ck = c[j] >> CSHIFT;
            int pos = atomicAdd(&s_cur[ck], 1);
            s_sorted[pos] = (r[j] << CSHIFT) | (c[j] & (CNODES - 1));
        }
    }
    __syncthreads();

    // coalesced run writes: consecutive i -> mostly same run -> consecutive global addrs
    for (int i = threadIdx.x; i < tilecount; i += PTPB) {
        int v = s_sorted[i];
        int lo = 0, hi = K;  // s_start[lo] <= i < s_start[hi]
        while (hi - lo > 1) {
            int mid = (lo + hi) >> 1;
            if (s_start[mid] <= i) lo = mid; else hi = mid;
        }
        packed[s_gbase[lo] + (i - s_start[lo])] = v;
    }
}

// ---------- pass 4: per-chunk degree -> dis, p ----------
__global__ __launch_bounds__(ATPB) void k_dis_p(
    const float* __restrict__ x, const int* __restrict__ packed,
    const int* __restrict__ bbase, float* __restrict__ dis, float* __restrict__ p, int n)
{
    __shared__ int cnt[CNODES];
    int k = blockIdx.x;
    int node0 = k << CSHIFT;
    int nn = min(CNODES, n - node0);
    for (int i = threadIdx.x; i < nn; i += ATPB) cnt[i] = 0;
    __syncthreads();
    int e0 = bbase[k], e1 = bbase[k + 1];
    int a0 = min((e0 + 3) & ~3, e1);
    int a1 = max(e1 & ~3, a0);
    for (int e = e0 + (int)threadIdx.x; e < a0; e += ATPB)
        atomicAdd(&cnt[packed[e] & (CNODES - 1)], 1);
    const int4* pk4 = (const int4*)packed;
    for (int i4 = (a0 >> 2) + (int)threadIdx.x; i4 < (a1 >> 2); i4 += ATPB) {
        int4 v = pk4[i4];
        atomicAdd(&cnt[v.x & (CNODES - 1)], 1);
        atomicAdd(&cnt[v.y & (CNODES - 1)], 1);
        atomicAdd(&cnt[v.z & (CNODES - 1)], 1);
        atomicAdd(&cnt[v.w & (CNODES - 1)], 1);
    }
    for (int e = a1 + (int)threadIdx.x; e < e1; e += ATPB)
        atomicAdd(&cnt[packed[e] & (CNODES - 1)], 1);
    __syncthreads();
    for (int i = threadIdx.x; i < nn; i += ATPB) {
        float d = (float)(cnt[i] + 1);          // +1 self-loop
        float ds = 1.0f / sqrtf(d);
        dis[node0 + i] = ds;
        p[node0 + i] = x[node0 + i] * ds;
    }
}

// ---------- pass 5: scalar aggregation + fused MLP -> gp ----------
__global__ __launch_bounds__(ATPB) void k_s_gp(
    const int* __restrict__ packed, const int* __restrict__ bbase,
    const float* __restrict__ p, const float* __restrict__ dis,
    const float* __restrict__ W1, const float* __restrict__ b1,
    const float* __restrict__ W2, float* __restrict__ gp, int n)
{
    __shared__ float s[CNODES];
    int k = blockIdx.x;
    int node0 = k << CSHIFT;
    int nn = min(CNODES, n - node0);
    for (int i = threadIdx.x; i < nn; i += ATPB) s[i] = 0.0f;
    __syncthreads();
    int e0 = bbase[k], e1 = bbase[k + 1];
    int a0 = min((e0 + 3) & ~3, e1);
    int a1 = max(e1 & ~3, a0);
    for (int e = e0 + (int)threadIdx.x; e < a0; e += ATPB) {
        int v = packed[e];
        atomicAdd(&s[v & (CNODES - 1)], p[((unsigned)v) >> CSHIFT]);
    }
    const int4* pk4 = (const int4*)packed;
    for (int i4 = (a0 >> 2) + (int)threadIdx.x; i4 < (a1 >> 2); i4 += ATPB) {
        int4 v = pk4[i4];
        atomicAdd(&s[v.x & (CNODES - 1)], p[((unsigned)v.x) >> CSHIFT]);
        atomicAdd(&s[v.y & (CNODES - 1)], p[((unsigned)v.y) >> CSHIFT]);
        atomicAdd(&s[v.z & (CNODES - 1)], p[((unsigned)v.z) >> CSHIFT]);
        atomicAdd(&s[v.w & (CNODES - 1)], p[((unsigned)v.w) >> CSHIFT]);
    }
    for (int e = a1 + (int)threadIdx.x; e < e1; e += ATPB) {
        int v = packed[e];
        atomicAdd(&s[v & (CNODES - 1)], p[((unsigned)v) >> CSHIFT]);
    }
    __syncthreads();
    float2* gp2 = (float2*)gp;
    for (int i = threadIdx.x; i < nn; i += ATPB) {
        int node = node0 + i;
        float d = dis[node];
        float a = d * (s[i] + p[node]);         // + self-loop term
        float g0 = 0.0f, g1 = 0.0f;
#pragma unroll
        for (int q = 0; q < 16; ++q) {
            float h = fmaxf(W1[q] * a + b1[q], 0.0f);
            g0 += h * W2[2 * q];
            g1 += h * W2[2 * q + 1];
        }
        gp2[node] = make_float2(g0 * d, g1 * d);
    }
}

// ---------- pass 6: float2 aggregation -> out ----------
__global__ __launch_bounds__(ATPB) void k_out(
    const int* __restrict__ packed, const int* __restrict__ bbase,
    const float* __restrict__ gp, const float* __restrict__ dis,
    const float* __restrict__ b2, float* __restrict__ out, int n)
{
    __shared__ float ox[CNODES];
    __shared__ float oy[CNODES];
    int k = blockIdx.x;
    int node0 = k << CSHIFT;
    int nn = min(CNODES, n - node0);
    for (int i = threadIdx.x; i < nn; i += ATPB) { ox[i] = 0.0f; oy[i] = 0.0f; }
    __syncthreads();
    int e0 = bbase[k], e1 = bbase[k + 1];
    int a0 = min((e0 + 3) & ~3, e1);
    int a1 = max(e1 & ~3, a0);
    const float2* gp2 = (const float2*)gp;
    for (int e = e0 + (int)threadIdx.x; e < a0; e += ATPB) {
        int v = packed[e];
        float2 g = gp2[((unsigned)v) >> CSHIFT];
        atomicAdd(&ox[v & (CNODES - 1)], g.x);
        atomicAdd(&oy[v & (CNODES - 1)], g.y);
    }
    const int4* pk4 = (const int4*)packed;
    for (int i4 = (a0 >> 2) + (int)threadIdx.x; i4 < (a1 >> 2); i4 += ATPB) {
        int4 v = pk4[i4];
        float2 g0 = gp2[((unsigned)v.x) >> CSHIFT];
        float2 g1 = gp2[((unsigned)v.y) >> CSHIFT];
        float2 g2 = gp2[((unsigned)v.z) >> CSHIFT];
        float2 g3 = gp2[((unsigned)v.w) >> CSHIFT];
        atomicAdd(&ox[v.x & (CNODES - 1)], g0.x);
        atomicAdd(&oy[v.x & (CNODES - 1)], g0.y);
        atomicAdd(&ox[v.y & (CNODES - 1)], g1.x);
        atomicAdd(&oy[v.y & (CNODES - 1)], g1.y);
        atomicAdd(&ox[v.z & (CNODES - 1)], g2.x);
        atomicAdd(&oy[v.z & (CNODES - 1)], g2.y);
        atomicAdd(&ox[v.w & (CNODES - 1)], g3.x);
        atomicAdd(&oy[v.w & (CNODES - 1)], g3.y);
    }
    for (int e = a1 + (int)threadIdx.x; e < e1; e += ATPB) {
        int v = packed[e];
        float2 g = gp2[((unsigned)v) >> CSHIFT];
        atomicAdd(&ox[v & (CNODES - 1)], g.x);
        atomicAdd(&oy[v & (CNODES - 1)], g.y);
    }
    __syncthreads();
    float b20 = b2[0], b21 = b2[1];
    float2* out2 = (float2*)out;
    for (int i = threadIdx.x; i < nn; i += ATPB) {
        int node = node0 + i;
        float d = dis[node];
        float2 g = gp2[node];
        out2[node] = make_float2(d * (ox[i] + g.x) + b20, d * (oy[i] + g.y) + b21);
    }
}

// ---------------- fallback path (R1, global atomics) ----------------

__global__ void f_init_deg(float* __restrict__ deg, int n) {
    int i = blockIdx.x * blockDim.x + threadIdx.x;
    if (i < n) deg[i] = 1.0f;
}
__global__ void f_deg(const int* __restrict__ col, float* __restrict__ deg, int ne) {
    int tid = blockIdx.x * blockDim.x + threadIdx.x;
    int stride = gridDim.x * blockDim.x;
    for (int e = tid; e < ne; e += stride) atomicAdd(&deg[col[e]], 1.0f);
}
__global__ void f_dis(const float* __restrict__ x, float* __restrict__ deg_dis,
                      float* __restrict__ p, float* __restrict__ s, int n) {
    int i = blockIdx.x * blockDim.x + threadIdx.x;
    if (i >= n) return;
    float dis = 1.0f / sqrtf(deg_dis[i]);
    deg_dis[i] = dis;
    float pv = x[i] * dis;
    p[i] = pv;
    s[i] = pv;
}
__global__ void f_scatter1(const int* __restrict__ row, const int* __restrict__ col,
                           const float* __restrict__ p, float* __restrict__ s, int ne) {
    int tid = blockIdx.x * blockDim.x + threadIdx.x;
    int stride = gridDim.x * blockDim.x;
    for (int e = tid; e < ne; e += stride) atomicAdd(&s[col[e]], p[row[e]]);
}
__global__ void f_node(const float* __restrict__ dis, const float* __restrict__ s,
                       const float* __restrict__ W1, const float* __restrict__ b1,
                       const float* __restrict__ W2,
                       float* __restrict__ gp, float* __restrict__ out, int n) {
    int i = blockIdx.x * blockDim.x + threadIdx.x;
    if (i >= n) return;
    float d = dis[i];
    float a = d * s[i];
    float g0 = 0.0f, g1 = 0.0f;
#pragma unroll
    for (int q = 0; q < 16; ++q) {
        float h = fmaxf(W1[q] * a + b1[q], 0.0f);
        g0 += h * W2[2 * q];
        g1 += h * W2[2 * q + 1];
    }
    ((float2*)gp)[i] = make_float2(g0 * d, g1 * d);
    ((float2*)out)[i] = make_float2(g0 * d, g1 * d);
}
__global__ void f_scatter2(const int* __restrict__ row, const int* __restrict__ col,
                           const float* __restrict__ gp, float* __restrict__ out, int ne) {
    int tid = blockIdx.x * blockDim.x + threadIdx.x;
    int stride = gridDim.x * blockDim.x;
    const float2* gp2 = (const float2*)gp;
    for (int e = tid; e < ne; e += stride) {
        float2 g = gp2[row[e]];
        atomicAdd(&out[2 * col[e]], g.x);
        atomicAdd(&out[2 * col[e] + 1], g.y);
    }
}
__global__ void f_final(const float* __restrict__ dis, const float* __restrict__ b2,
                        float* __restrict__ out, int n) {
    int i = blockIdx.x * blockDim.x + threadIdx.x;
    if (i >= n) return;
    float d = dis[i];
    float2* out2 = (float2*)out;
    float2 t = out2[i];
    out2[i] = make_float2(d * t.x + b2[0], d * t.y + b2[1]);
}

// ---------------- launch ----------------

extern "C" void kernel_launch(void* const* d_in, const int* in_sizes, int n_in,
                              void* d_out, int out_size, void* d_ws, size_t ws_size,
                              hipStream_t stream) {
    const float* x = (const float*)d_in[0];
    const int* edge_index = (const int*)d_in[1];
    const float* W1 = (const float*)d_in[2];
    const float* b1 = (const float*)d_in[3];
    const float* W2 = (const float*)d_in[4];
    const float* b2 = (const float*)d_in[5];
    float* out = (float*)d_out;

    int n = in_sizes[0];
    int ne = in_sizes[1] / 2;
    const int* row = edge_index;
    const int* col = edge_index + ne;

    int K = (n + CNODES - 1) >> CSHIFT;

    size_t off = 0;
    auto alloc = [&](size_t bytes) -> char* {
        char* ptr = (char*)d_ws + off;
        off += (bytes + 255) & ~(size_t)255;
        return ptr;
    };
    int* totals = (int*)alloc((size_t)K * sizeof(int));
    int* bbase  = (int*)alloc((size_t)(K + 1) * sizeof(int));
    int* cursor = (int*)alloc((size_t)K * sizeof(int));
    int* packed = (int*)alloc((size_t)ne * sizeof(int));
    float* dis  = (float*)alloc((size_t)n * sizeof(float));
    float* p    = (float*)alloc((size_t)n * sizeof(float));
    float* gp   = (float*)alloc((size_t)n * 2 * sizeof(float));

    bool fast = (off <= ws_size) && (K >= 1) && (K <= CMAX) && (K <= PTPB) && (ne > 0);

    if (fast) {
        int partBlocks = (ne + PTILE - 1) / PTILE;
        k_zero<<<(K + 255) / 256, 256, 0, stream>>>(totals, K);
        k_count<<<1024, 256, 0, stream>>>(col, ne, totals, K);
        k_scan<<<1, 64, 0, stream>>>(totals, bbase, cursor, K);
        k_partition<<<partBlocks, PTPB, 0, stream>>>(row, col, ne, cursor, packed, K);
        k_dis_p<<<K, ATPB, 0, stream>>>(x, packed, bbase, dis, p, n);
        k_s_gp<<<K, ATPB, 0, stream>>>(packed, bbase, p, dis, W1, b1, W2, gp, n);
        k_out<<<K, ATPB, 0, stream>>>(packed, bbase, gp, dis, b2, out, n);
    } else {
        float* ws = (float*)d_ws;
        float* deg_dis = ws;
        float* pp = ws + n;
        float* ss = ws + 2 * (size_t)n;
        float* gpp = ws + 3 * (size_t)n;
        int nodeBlocks = (n + 255) / 256;
        int edgeBlocks = 4096;
        f_init_deg<<<nodeBlocks, 256, 0, stream>>>(deg_dis, n);
        f_deg<<<edgeBlocks, 256, 0, stream>>>(col, deg_dis, ne);
        f_dis<<<nodeBlocks, 256, 0, stream>>>(x, deg_dis, pp, ss, n);
        f_scatter1<<<edgeBlocks, 256, 0, stream>>>(row, col, pp, ss, ne);
        f_node<<<nodeBlocks, 256, 0, stream>>>(deg_dis, ss, W1, b1, W2, gpp, out, n);
        f_scatter2<<<edgeBlocks, 256, 0, stream>>>(row, col, gpp, out, ne);
        f_final<<<nodeBlocks, 256, 0, stream>>>(deg_dis, b2, out, n);
    }
}

// Round 4
// 428.792 us; speedup vs baseline: 1.5056x; 1.5056x over previous
//
#include <hip/hip_runtime.h>

// GCN 2-layer collapsed (x is [N,1] => layer 1 is rank-1):
//   out[c] = dis[c]*(sum_{r->c} gp[r] + gp[c]) + b2,  gp[r] = (relu(W1*a[r]+b1)@W2)*dis[r]
//   a[r]   = dis[r]*(sum_{r'->r} p[r'] + p[r]),       p[r']=x[r']*dis[r'], dis=1/sqrt(deg+1)
//
// R1: global atomics = 20G/s fabric wall (3.1ms).
// R2: 512-node buckets + LDS atomics (478us) - partition scattered 4B stores = 390MB writes.
// R3: tile-local LDS counting sort (coalesced runs) but 4096-node chunks -> K=123 blocks
//     = parallelism cliff in aggregation (occupancy 11%, k_out 340us). Total 646us.
// R4: keep sort-based partition, 1024-node chunks (K=489) -> >=2 blocks/CU in aggregation,
//     4-8KB LDS accumulators, 256-thread aggregation blocks.

#define CSHIFT 10
#define CNODES 1024          // 1 << CSHIFT
#define CMAX   512           // max chunks supported (n <= 512K)

#define PTPB  512            // partition block
#define PU    16             // edges per thread
#define PTILE (PTPB * PU)    // 8192 edges per tile

#define ATPB  256            // aggregation block

// ---------- pass 0: zero chunk totals ----------
__global__ void k_zero(int* __restrict__ totals, int K) {
    int i = blockIdx.x * blockDim.x + threadIdx.x;
    if (i < K) totals[i] = 0;
}

// ---------- pass 1: chunk histogram ----------
__global__ void k_count(const int* __restrict__ col, int ne,
                        int* __restrict__ totals, int K) {
    __shared__ int cnt[CMAX];
    for (int i = threadIdx.x; i < K; i += blockDim.x) cnt[i] = 0;
    __syncthreads();
    int tid = blockIdx.x * blockDim.x + threadIdx.x;
    int stride = gridDim.x * blockDim.x;
    int ne4 = ne >> 2;
    const int4* col4 = (const int4*)col;
    for (int e = tid; e < ne4; e += stride) {
        int4 cc = col4[e];
        atomicAdd(&cnt[cc.x >> CSHIFT], 1);
        atomicAdd(&cnt[cc.y >> CSHIFT], 1);
        atomicAdd(&cnt[cc.z >> CSHIFT], 1);
        atomicAdd(&cnt[cc.w >> CSHIFT], 1);
    }
    for (int e = (ne4 << 2) + tid; e < ne; e += stride)
        atomicAdd(&cnt[col[e] >> CSHIFT], 1);
    __syncthreads();
    for (int i = threadIdx.x; i < K; i += blockDim.x)
        if (cnt[i]) atomicAdd(&totals[i], cnt[i]);
}

// ---------- pass 2: scan -> bbase, init cursors ----------
__global__ void k_scan(const int* __restrict__ totals, int* __restrict__ bbase,
                       int* __restrict__ cursor, int K) {
    if (threadIdx.x == 0 && blockIdx.x == 0) {
        int run = 0;
        for (int k = 0; k < K; ++k) {
            bbase[k] = run;
            cursor[k] = run;
            run += totals[k];
        }
        bbase[K] = run;
    }
}

// ---------- pass 3: partition with tile-local LDS counting sort ----------
__global__ __launch_bounds__(PTPB) void k_partition(
    const int* __restrict__ row, const int* __restrict__ col, int ne,
    int* __restrict__ cursor, int* __restrict__ packed, int K)
{
    __shared__ int s_cnt[CMAX];
    __shared__ int s_start[CMAX + 1];
    __shared__ int s_cur[CMAX];
    __shared__ int s_gbase[CMAX];
    __shared__ int s_sorted[PTILE];

    int tb = blockIdx.x * PTILE;
    int tilecount = ne - tb;
    if (tilecount > PTILE) tilecount = PTILE;

    for (int i = threadIdx.x; i < K; i += PTPB) s_cnt[i] = 0;
    __syncthreads();

    int r[PU], c[PU];
    const int4* row4 = (const int4*)row;
    const int4* col4 = (const int4*)col;
    int tb4 = tb >> 2;
#pragma unroll
    for (int j = 0; j < PU / 4; ++j) {
        int g4 = tb4 + j * PTPB + threadIdx.x;
        int e = g4 << 2;
        if (e + 3 < ne) {
            int4 rr = row4[g4];
            int4 cc = col4[g4];
            r[4 * j + 0] = rr.x; r[4 * j + 1] = rr.y; r[4 * j + 2] = rr.z; r[4 * j + 3] = rr.w;
            c[4 * j + 0] = cc.x; c[4 * j + 1] = cc.y; c[4 * j + 2] = cc.z; c[4 * j + 3] = cc.w;
        } else {
#pragma unroll
            for (int q = 0; q < 4; ++q) {
                int e2 = e + q;
                if (e2 < ne) { r[4 * j + q] = row[e2]; c[4 * j + q] = col[e2]; }
                else { r[4 * j + q] = 0; c[4 * j + q] = -1; }
            }
        }
    }
#pragma unroll
    for (int j = 0; j < PU; ++j)
        if (c[j] >= 0) atomicAdd(&s_cnt[c[j] >> CSHIFT], 1);
    __syncthreads();

    if (threadIdx.x == 0) {
        int run = 0;
        for (int k = 0; k < K; ++k) { s_start[k] = run; run += s_cnt[k]; }
        s_start[K] = run;  // == tilecount
    }
    __syncthreads();
    if ((int)threadIdx.x < K) {
        int n0 = s_cnt[threadIdx.x];
        s_gbase[threadIdx.x] = n0 ? atomicAdd(&cursor[threadIdx.x], n0) : 0;
        s_cur[threadIdx.x] = s_start[threadIdx.x];
    }
    __syncthreads();

#pragma unroll
    for (int j = 0; j < PU; ++j) {
        if (c[j] >= 0) {
            int ck = c[j] >> CSHIFT;
            int pos = atomicAdd(&s_cur[ck], 1);
            s_sorted[pos] = (r[j] << CSHIFT) | (c[j] & (CNODES - 1));
        }
    }
    __syncthreads();

    // coalesced run writes: consecutive i -> mostly same run -> consecutive global addrs
    for (int i = threadIdx.x; i < tilecount; i += PTPB) {
        int v = s_sorted[i];
        int lo = 0, hi = K;  // s_start[lo] <= i < s_start[hi]
        while (hi - lo > 1) {
            int mid = (lo + hi) >> 1;
            if (s_start[mid] <= i) lo = mid; else hi = mid;
        }
        packed[s_gbase[lo] + (i - s_start[lo])] = v;
    }
}

// ---------- pass 4: per-chunk degree -> dis, p ----------
__global__ __launch_bounds__(ATPB) void k_dis_p(
    const float* __restrict__ x, const int* __restrict__ packed,
    const int* __restrict__ bbase, float* __restrict__ dis, float* __restrict__ p, int n)
{
    __shared__ int cnt[CNODES];
    int k = blockIdx.x;
    int node0 = k << CSHIFT;
    int nn = min(CNODES, n - node0);
    for (int i = threadIdx.x; i < nn; i += ATPB) cnt[i] = 0;
    __syncthreads();
    int e0 = bbase[k], e1 = bbase[k + 1];
    int a0 = min((e0 + 3) & ~3, e1);
    int a1 = max(e1 & ~3, a0);
    for (int e = e0 + (int)threadIdx.x; e < a0; e += ATPB)
        atomicAdd(&cnt[packed[e] & (CNODES - 1)], 1);
    const int4* pk4 = (const int4*)packed;
    for (int i4 = (a0 >> 2) + (int)threadIdx.x; i4 < (a1 >> 2); i4 += ATPB) {
        int4 v = pk4[i4];
        atomicAdd(&cnt[v.x & (CNODES - 1)], 1);
        atomicAdd(&cnt[v.y & (CNODES - 1)], 1);
        atomicAdd(&cnt[v.z & (CNODES - 1)], 1);
        atomicAdd(&cnt[v.w & (CNODES - 1)], 1);
    }
    for (int e = a1 + (int)threadIdx.x; e < e1; e += ATPB)
        atomicAdd(&cnt[packed[e] & (CNODES - 1)], 1);
    __syncthreads();
    for (int i = threadIdx.x; i < nn; i += ATPB) {
        float d = (float)(cnt[i] + 1);          // +1 self-loop
        float ds = 1.0f / sqrtf(d);
        dis[node0 + i] = ds;
        p[node0 + i] = x[node0 + i] * ds;
    }
}

// ---------- pass 5: scalar aggregation + fused MLP -> gp ----------
__global__ __launch_bounds__(ATPB) void k_s_gp(
    const int* __restrict__ packed, const int* __restrict__ bbase,
    const float* __restrict__ p, const float* __restrict__ dis,
    const float* __restrict__ W1, const float* __restrict__ b1,
    const float* __restrict__ W2, float* __restrict__ gp, int n)
{
    __shared__ float s[CNODES];
    int k = blockIdx.x;
    int node0 = k << CSHIFT;
    int nn = min(CNODES, n - node0);
    for (int i = threadIdx.x; i < nn; i += ATPB) s[i] = 0.0f;
    __syncthreads();
    int e0 = bbase[k], e1 = bbase[k + 1];
    int a0 = min((e0 + 3) & ~3, e1);
    int a1 = max(e1 & ~3, a0);
    for (int e = e0 + (int)threadIdx.x; e < a0; e += ATPB) {
        int v = packed[e];
        atomicAdd(&s[v & (CNODES - 1)], p[((unsigned)v) >> CSHIFT]);
    }
    const int4* pk4 = (const int4*)packed;
    for (int i4 = (a0 >> 2) + (int)threadIdx.x; i4 < (a1 >> 2); i4 += ATPB) {
        int4 v = pk4[i4];
        atomicAdd(&s[v.x & (CNODES - 1)], p[((unsigned)v.x) >> CSHIFT]);
        atomicAdd(&s[v.y & (CNODES - 1)], p[((unsigned)v.y) >> CSHIFT]);
        atomicAdd(&s[v.z & (CNODES - 1)], p[((unsigned)v.z) >> CSHIFT]);
        atomicAdd(&s[v.w & (CNODES - 1)], p[((unsigned)v.w) >> CSHIFT]);
    }
    for (int e = a1 + (int)threadIdx.x; e < e1; e += ATPB) {
        int v = packed[e];
        atomicAdd(&s[v & (CNODES - 1)], p[((unsigned)v) >> CSHIFT]);
    }
    __syncthreads();
    float2* gp2 = (float2*)gp;
    for (int i = threadIdx.x; i < nn; i += ATPB) {
        int node = node0 + i;
        float d = dis[node];
        float a = d * (s[i] + p[node]);         // + self-loop term
        float g0 = 0.0f, g1 = 0.0f;
#pragma unroll
        for (int q = 0; q < 16; ++q) {
            float h = fmaxf(W1[q] * a + b1[q], 0.0f);
            g0 += h * W2[2 * q];
            g1 += h * W2[2 * q + 1];
        }
        gp2[node] = make_float2(g0 * d, g1 * d);
    }
}

// ---------- pass 6: float2 aggregation -> out ----------
__global__ __launch_bounds__(ATPB) void k_out(
    const int* __restrict__ packed, const int* __restrict__ bbase,
    const float* __restrict__ gp, const float* __restrict__ dis,
    const float* __restrict__ b2, float* __restrict__ out, int n)
{
    __shared__ float ox[CNODES];
    __shared__ float oy[CNODES];
    int k = blockIdx.x;
    int node0 = k << CSHIFT;
    int nn = min(CNODES, n - node0);
    for (int i = threadIdx.x; i < nn; i += ATPB) { ox[i] = 0.0f; oy[i] = 0.0f; }
    __syncthreads();
    int e0 = bbase[k], e1 = bbase[k + 1];
    int a0 = min((e0 + 3) & ~3, e1);
    int a1 = max(e1 & ~3, a0);
    const float2* gp2 = (const float2*)gp;
    for (int e = e0 + (int)threadIdx.x; e < a0; e += ATPB) {
        int v = packed[e];
        float2 g = gp2[((unsigned)v) >> CSHIFT];
        atomicAdd(&ox[v & (CNODES - 1)], g.x);
        atomicAdd(&oy[v & (CNODES - 1)], g.y);
    }
    const int4* pk4 = (const int4*)packed;
    for (int i4 = (a0 >> 2) + (int)threadIdx.x; i4 < (a1 >> 2); i4 += ATPB) {
        int4 v = pk4[i4];
        float2 g0 = gp2[((unsigned)v.x) >> CSHIFT];
        float2 g1 = gp2[((unsigned)v.y) >> CSHIFT];
        float2 g2 = gp2[((unsigned)v.z) >> CSHIFT];
        float2 g3 = gp2[((unsigned)v.w) >> CSHIFT];
        atomicAdd(&ox[v.x & (CNODES - 1)], g0.x);
        atomicAdd(&oy[v.x & (CNODES - 1)], g0.y);
        atomicAdd(&ox[v.y & (CNODES - 1)], g1.x);
        atomicAdd(&oy[v.y & (CNODES - 1)], g1.y);
        atomicAdd(&ox[v.z & (CNODES - 1)], g2.x);
        atomicAdd(&oy[v.z & (CNODES - 1)], g2.y);
        atomicAdd(&ox[v.w & (CNODES - 1)], g3.x);
        atomicAdd(&oy[v.w & (CNODES - 1)], g3.y);
    }
    for (int e = a1 + (int)threadIdx.x; e < e1; e += ATPB) {
        int v = packed[e];
        float2 g = gp2[((unsigned)v) >> CSHIFT];
        atomicAdd(&ox[v & (CNODES - 1)], g.x);
        atomicAdd(&oy[v & (CNODES - 1)], g.y);
    }
    __syncthreads();
    float b20 = b2[0], b21 = b2[1];
    float2* out2 = (float2*)out;
    for (int i = threadIdx.x; i < nn; i += ATPB) {
        int node = node0 + i;
        float d = dis[node];
        float2 g = gp2[node];
        out2[node] = make_float2(d * (ox[i] + g.x) + b20, d * (oy[i] + g.y) + b21);
    }
}

// ---------------- fallback path (R1, global atomics) ----------------

__global__ void f_init_deg(float* __restrict__ deg, int n) {
    int i = blockIdx.x * blockDim.x + threadIdx.x;
    if (i < n) deg[i] = 1.0f;
}
__global__ void f_deg(const int* __restrict__ col, float* __restrict__ deg, int ne) {
    int tid = blockIdx.x * blockDim.x + threadIdx.x;
    int stride = gridDim.x * blockDim.x;
    for (int e = tid; e < ne; e += stride) atomicAdd(&deg[col[e]], 1.0f);
}
__global__ void f_dis(const float* __restrict__ x, float* __restrict__ deg_dis,
                      float* __restrict__ p, float* __restrict__ s, int n) {
    int i = blockIdx.x * blockDim.x + threadIdx.x;
    if (i >= n) return;
    float dis = 1.0f / sqrtf(deg_dis[i]);
    deg_dis[i] = dis;
    float pv = x[i] * dis;
    p[i] = pv;
    s[i] = pv;
}
__global__ void f_scatter1(const int* __restrict__ row, const int* __restrict__ col,
                           const float* __restrict__ p, float* __restrict__ s, int ne) {
    int tid = blockIdx.x * blockDim.x + threadIdx.x;
    int stride = gridDim.x * blockDim.x;
    for (int e = tid; e < ne; e += stride) atomicAdd(&s[col[e]], p[row[e]]);
}
__global__ void f_node(const float* __restrict__ dis, const float* __restrict__ s,
                       const float* __restrict__ W1, const float* __restrict__ b1,
                       const float* __restrict__ W2,
                       float* __restrict__ gp, float* __restrict__ out, int n) {
    int i = blockIdx.x * blockDim.x + threadIdx.x;
    if (i >= n) return;
    float d = dis[i];
    float a = d * s[i];
    float g0 = 0.0f, g1 = 0.0f;
#pragma unroll
    for (int q = 0; q < 16; ++q) {
        float h = fmaxf(W1[q] * a + b1[q], 0.0f);
        g0 += h * W2[2 * q];
        g1 += h * W2[2 * q + 1];
    }
    ((float2*)gp)[i] = make_float2(g0 * d, g1 * d);
    ((float2*)out)[i] = make_float2(g0 * d, g1 * d);
}
__global__ void f_scatter2(const int* __restrict__ row, const int* __restrict__ col,
                           const float* __restrict__ gp, float* __restrict__ out, int ne) {
    int tid = blockIdx.x * blockDim.x + threadIdx.x;
    int stride = gridDim.x * blockDim.x;
    const float2* gp2 = (const float2*)gp;
    for (int e = tid; e < ne; e += stride) {
        float2 g = gp2[row[e]];
        atomicAdd(&out[2 * col[e]], g.x);
        atomicAdd(&out[2 * col[e] + 1], g.y);
    }
}
__global__ void f_final(const float* __restrict__ dis, const float* __restrict__ b2,
                        float* __restrict__ out, int n) {
    int i = blockIdx.x * blockDim.x + threadIdx.x;
    if (i >= n) return;
    float d = dis[i];
    float2* out2 = (float2*)out;
    float2 t = out2[i];
    out2[i] = make_float2(d * t.x + b2[0], d * t.y + b2[1]);
}

// ---------------- launch ----------------

extern "C" void kernel_launch(void* const* d_in, const int* in_sizes, int n_in,
                              void* d_out, int out_size, void* d_ws, size_t ws_size,
                              hipStream_t stream) {
    const float* x = (const float*)d_in[0];
    const int* edge_index = (const int*)d_in[1];
    const float* W1 = (const float*)d_in[2];
    const float* b1 = (const float*)d_in[3];
    const float* W2 = (const float*)d_in[4];
    const float* b2 = (const float*)d_in[5];
    float* out = (float*)d_out;

    int n = in_sizes[0];
    int ne = in_sizes[1] / 2;
    const int* row = edge_index;
    const int* col = edge_index + ne;

    int K = (n + CNODES - 1) >> CSHIFT;

    size_t off = 0;
    auto alloc = [&](size_t bytes) -> char* {
        char* ptr = (char*)d_ws + off;
        off += (bytes + 255) & ~(size_t)255;
        return ptr;
    };
    int* totals = (int*)alloc((size_t)K * sizeof(int));
    int* bbase  = (int*)alloc((size_t)(K + 1) * sizeof(int));
    int* cursor = (int*)alloc((size_t)K * sizeof(int));
    int* packed = (int*)alloc((size_t)ne * sizeof(int));
    float* dis  = (float*)alloc((size_t)n * sizeof(float));
    float* p    = (float*)alloc((size_t)n * sizeof(float));
    float* gp   = (float*)alloc((size_t)n * 2 * sizeof(float));

    bool fast = (off <= ws_size) && (K >= 1) && (K <= CMAX) && (K <= PTPB) && (ne > 0);

    if (fast) {
        int partBlocks = (ne + PTILE - 1) / PTILE;
        k_zero<<<(K + 255) / 256, 256, 0, stream>>>(totals, K);
        k_count<<<1024, 256, 0, stream>>>(col, ne, totals, K);
        k_scan<<<1, 64, 0, stream>>>(totals, bbase, cursor, K);
        k_partition<<<partBlocks, PTPB, 0, stream>>>(row, col, ne, cursor, packed, K);
        k_dis_p<<<K, ATPB, 0, stream>>>(x, packed, bbase, dis, p, n);
        k_s_gp<<<K, ATPB, 0, stream>>>(packed, bbase, p, dis, W1, b1, W2, gp, n);
        k_out<<<K, ATPB, 0, stream>>>(packed, bbase, gp, dis, b2, out, n);
    } else {
        float* ws = (float*)d_ws;
        float* deg_dis = ws;
        float* pp = ws + n;
        float* ss = ws + 2 * (size_t)n;
        float* gpp = ws + 3 * (size_t)n;
        int nodeBlocks = (n + 255) / 256;
        int edgeBlocks = 4096;
        f_init_deg<<<nodeBlocks, 256, 0, stream>>>(deg_dis, n);
        f_deg<<<edgeBlocks, 256, 0, stream>>>(col, deg_dis, ne);
        f_dis<<<nodeBlocks, 256, 0, stream>>>(x, deg_dis, pp, ss, n);
        f_scatter1<<<edgeBlocks, 256, 0, stream>>>(row, col, pp, ss, ne);
        f_node<<<nodeBlocks, 256, 0, stream>>>(deg_dis, ss, W1, b1, W2, gpp, out, n);
        f_scatter2<<<edgeBlocks, 256, 0, stream>>>(row, col, gpp, out, ne);
        f_final<<<nodeBlocks, 256, 0, stream>>>(deg_dis, b2, out, n);
    }
}